// Round 1
// baseline (246.801 us; speedup 1.0000x reference)
//
#include <hip/hip_runtime.h>
#include <math.h>

#define THREADS 256
#define MAX_ROW_ITERS 8   // supports N up to 8192 with 256 threads * float4

// ---------------- Kernel 1a: column partial sums of W (deterministic) -------
__global__ __launch_bounds__(THREADS)
void colsum_partials_kernel(const float* __restrict__ W, float* __restrict__ partials,
                            int O, int N, int rows_per_chunk) {
    int col = (blockIdx.x * THREADS + threadIdx.x) * 4;
    if (col >= N) return;
    int r0 = blockIdx.y * rows_per_chunk;
    int r1 = r0 + rows_per_chunk; if (r1 > O) r1 = O;
    float ax = 0.f, ay = 0.f, az = 0.f, aw = 0.f;
    for (int r = r0; r < r1; ++r) {
        const float4 v = *reinterpret_cast<const float4*>(W + (size_t)r * N + col);
        ax += v.x; ay += v.y; az += v.z; aw += v.w;
    }
    float4* p = reinterpret_cast<float4*>(partials + (size_t)blockIdx.y * N + col);
    *p = make_float4(ax, ay, az, aw);
}

// ---------------- Kernel 1b: reduce partials -> c ----------------------------
__global__ __launch_bounds__(THREADS)
void colsum_reduce_kernel(const float* __restrict__ partials, float* __restrict__ c,
                          int N, int chunks) {
    int col = (blockIdx.x * THREADS + threadIdx.x) * 4;
    if (col >= N) return;
    float ax = 0.f, ay = 0.f, az = 0.f, aw = 0.f;
    for (int k = 0; k < chunks; ++k) {
        const float4 v = *reinterpret_cast<const float4*>(partials + (size_t)k * N + col);
        ax += v.x; ay += v.y; az += v.z; aw += v.w;
    }
    *reinterpret_cast<float4*>(c + col) = make_float4(ax, ay, az, aw);
}

// ---------------- Kernel 1 (fallback): atomic column sums --------------------
__global__ __launch_bounds__(THREADS)
void colsum_atomic_kernel(const float* __restrict__ W, float* __restrict__ c,
                          int O, int N, int rows_per_chunk) {
    int col = (blockIdx.x * THREADS + threadIdx.x) * 4;
    if (col >= N) return;
    int r0 = blockIdx.y * rows_per_chunk;
    int r1 = r0 + rows_per_chunk; if (r1 > O) r1 = O;
    float ax = 0.f, ay = 0.f, az = 0.f, aw = 0.f;
    for (int r = r0; r < r1; ++r) {
        const float4 v = *reinterpret_cast<const float4*>(W + (size_t)r * N + col);
        ax += v.x; ay += v.y; az += v.z; aw += v.w;
    }
    atomicAdd(&c[col + 0], ax);
    atomicAdd(&c[col + 1], ay);
    atomicAdd(&c[col + 2], az);
    atomicAdd(&c[col + 3], aw);
}

// ---------------- Kernel 2: sum(bias - subtract) -----------------------------
__global__ __launch_bounds__(THREADS)
void biassum_kernel(const float* __restrict__ bias, const float* __restrict__ sub,
                    float* __restrict__ out_scalar, int O) {
    float s = 0.f;
    for (int i = threadIdx.x; i < O; i += THREADS) s += bias[i] - sub[i];
    // wave reduce (64 lanes)
    #pragma unroll
    for (int off = 32; off > 0; off >>= 1) s += __shfl_down(s, off, 64);
    __shared__ float lds[THREADS / 64];
    int wave = threadIdx.x >> 6;
    if ((threadIdx.x & 63) == 0) lds[wave] = s;
    __syncthreads();
    if (threadIdx.x == 0) {
        float t = 0.f;
        #pragma unroll
        for (int w = 0; w < THREADS / 64; ++w) t += lds[w];
        *out_scalar = t;
    }
}

// ---------------- Kernel 3: fused row dot -> gelu -> residual add ------------
// One block per row. x row held in registers: read once, write out once.
__global__ __launch_bounds__(THREADS)
void row_fused_kernel(const float* __restrict__ x, const float* __restrict__ c,
                      const float* __restrict__ cb, const int* __restrict__ of_ptr,
                      float* __restrict__ out, int N) {
    const int m = blockIdx.x;
    const size_t base = (size_t)m * N;
    const int iters = N / (THREADS * 4);

    float4 xv[MAX_ROW_ITERS];
    float partial = 0.f;
    #pragma unroll
    for (int it = 0; it < MAX_ROW_ITERS; ++it) {
        if (it < iters) {
            const int idx = (it * THREADS + threadIdx.x) * 4;
            const float4 xx = *reinterpret_cast<const float4*>(x + base + idx);
            const float4 cc = *reinterpret_cast<const float4*>(c + idx);
            xv[it] = xx;
            partial += xx.x * cc.x + xx.y * cc.y + xx.z * cc.z + xx.w * cc.w;
        }
    }

    // wave reduce across 64 lanes
    #pragma unroll
    for (int off = 32; off > 0; off >>= 1) partial += __shfl_down(partial, off, 64);

    __shared__ float lds[THREADS / 64];
    __shared__ float gsh;
    const int wave = threadIdx.x >> 6;
    if ((threadIdx.x & 63) == 0) lds[wave] = partial;
    __syncthreads();
    if (threadIdx.x == 0) {
        float rs = 0.f;
        #pragma unroll
        for (int w = 0; w < THREADS / 64; ++w) rs += lds[w];
        rs += *cb;
        const float of = (float)(*of_ptr);
        const float mm = rs / of;
        const float inner = 0.7978845608028654f * (mm + 0.044715f * mm * mm * mm);
        gsh = 0.5f * mm * (1.0f + tanhf(inner));
    }
    __syncthreads();
    const float g = gsh;

    #pragma unroll
    for (int it = 0; it < MAX_ROW_ITERS; ++it) {
        if (it < iters) {
            const int idx = (it * THREADS + threadIdx.x) * 4;
            const float4 xx = xv[it];
            *reinterpret_cast<float4*>(out + base + idx) =
                make_float4(xx.x + g, xx.y + g, xx.z + g, xx.w + g);
        }
    }
}

extern "C" void kernel_launch(void* const* d_in, const int* in_sizes, int n_in,
                              void* d_out, int out_size, void* d_ws, size_t ws_size,
                              hipStream_t stream) {
    const float* x    = (const float*)d_in[0];
    const float* W    = (const float*)d_in[1];
    const float* bias = (const float*)d_in[2];
    const float* sub  = (const float*)d_in[3];
    const int* of_ptr = (const int*)d_in[4];

    const int O = in_sizes[2];                       // 16384
    const int N = (int)((long long)in_sizes[1] / O); // 4096
    const int M = (int)((long long)in_sizes[0] / N); // 16384

    float* ws = (float*)d_ws;
    float* c  = ws;            // N floats
    float* cb = ws + N;        // 1 float (padded to 64)
    float* partials = ws + N + 64;

    const int colblocks = (N + THREADS * 4 - 1) / (THREADS * 4); // 4 for N=4096

    const int CHUNKS = 128;
    const int rows_per_chunk = (O + CHUNKS - 1) / CHUNKS;
    const size_t need = ((size_t)N + 64 + (size_t)CHUNKS * N) * sizeof(float);

    if (ws_size >= need) {
        // deterministic two-stage column sum
        dim3 g1(colblocks, CHUNKS);
        colsum_partials_kernel<<<g1, THREADS, 0, stream>>>(W, partials, O, N, rows_per_chunk);
        colsum_reduce_kernel<<<colblocks, THREADS, 0, stream>>>(partials, c, N, CHUNKS);
    } else {
        // fallback: atomic accumulation (needs zeroed c)
        hipMemsetAsync(c, 0, (size_t)N * sizeof(float), stream);
        dim3 g1(colblocks, CHUNKS);
        colsum_atomic_kernel<<<g1, THREADS, 0, stream>>>(W, c, O, N, rows_per_chunk);
    }

    biassum_kernel<<<1, THREADS, 0, stream>>>(bias, sub, cb, O);

    row_fused_kernel<<<M, THREADS, 0, stream>>>(x, c, cb, of_ptr, (float*)d_out, N);
}